// Round 4
// baseline (3838.940 us; speedup 1.0000x reference)
//
#include <hip/hip_runtime.h>
#include <hip/hip_bf16.h>
#include <cstdint>

#define B 2048
#define NL 32
#define FEAT 512
#define HID 512
#define HW 64
#define OUTSZ 42
#define G3 1536
#define LDIH 554   // gru_w_ih row stride
#define KC 576     // K for ghss GEMM: 512 h + 42 ss + 22 pad
#define MB 32      // batch rows per block
#define NBLK (B/MB)
#define LDX 584    // lds_x row stride (576 + 8 pad)
#define LDH 520    // hrelu/o1 row stride (512 + 8 pad)

typedef __bf16 bf16x8 __attribute__((ext_vector_type(8)));
typedef float f32x4 __attribute__((ext_vector_type(4)));
typedef __hip_bfloat16 bf16_t;

static __device__ __forceinline__ float sigmoidf_(float x){ return 1.f/(1.f+__expf(-x)); }

// ---------------- one-time weight prep ----------------
// w_perm [1536][576]: permuted N so wave w (of 8) owns rows [w*192, w*192+192)
//   = {r-gate cols 64w..64w+63, z-gate, n-gate}. cols: 0..511 = w_hh,
//   512..553 = w_ih ss-cols for r/z rows only (zero for n rows), rest 0.
// w_ssn [512][64]: w_ih n-rows ss-cols (input-side n contribution), padded.
// lin1_wb [512][512], lin2_wp [48][512] (rows 42..47 zero), w_ih512b [1536][512].
// bias_comb [1536] = b_ih + (gate<2 ? b_hh : 0)  (n-gate's b_hh stays hidden-side)
__global__ __launch_bounds__(256) void prep2_kernel(
    const float* __restrict__ w_ih, const float* __restrict__ w_hh,
    const float* __restrict__ lin1_w, const float* __restrict__ lin2_w,
    const float* __restrict__ b_ih, const float* __restrict__ b_hh,
    bf16_t* __restrict__ w_perm, bf16_t* __restrict__ w_ssn,
    bf16_t* __restrict__ lin1_wb, bf16_t* __restrict__ lin2_wp,
    bf16_t* __restrict__ w_ih512b, float* __restrict__ bias_comb){
  const int NP = G3*KC, NS = 512*64, NL1 = 512*512, NL2 = 48*512, NI = G3*512, NB = G3;
  const int total = NP+NS+NL1+NL2+NI+NB;
  for (int idx = blockIdx.x*256 + threadIdx.x; idx < total; idx += gridDim.x*256){
    int i = idx;
    if (i < NP){
      int p = i / KC, k = i % KC;
      int c = p / 192, u = p % 192, g = u >> 6, jl = u & 63;
      int orig = g*512 + c*64 + jl;
      float v = (k < 512) ? w_hh[orig*512 + k]
              : ((k < 512 + OUTSZ && g < 2) ? w_ih[(size_t)orig*LDIH + k] : 0.f);
      w_perm[i] = __float2bfloat16(v);
    } else if ((i -= NP) < NS){
      int j = i >> 6, k = i & 63;
      float v = (k < OUTSZ) ? w_ih[(size_t)(1024+j)*LDIH + 512 + k] : 0.f;
      w_ssn[i] = __float2bfloat16(v);
    } else if ((i -= NS) < NL1){
      lin1_wb[i] = __float2bfloat16(lin1_w[i]);
    } else if ((i -= NL1) < NL2){
      int j = i >> 9, k = i & 511;
      lin2_wp[i] = __float2bfloat16(j < OUTSZ ? lin2_w[j*512 + k] : 0.f);
    } else if ((i -= NL2) < NI){
      int r = i >> 9, c = i & 511;
      w_ih512b[i] = __float2bfloat16(w_ih[(size_t)r*LDIH + c]);
    } else {
      int j = i - NI;
      bias_comb[j] = b_ih[j] + (j < 1024 ? b_hh[j] : 0.f);
    }
  }
}

// ---------------- attention precompute (step-invariant) ----------------
__global__ __launch_bounds__(256) void att_kernel(const float* __restrict__ feat,
                                                  const float* __restrict__ att_w,
                                                  bf16_t* __restrict__ att_feat){
  int b = blockIdx.x;
  const float* fb = feat + (size_t)b * FEAT * HW;
  __shared__ float part[4][64];
  __shared__ float attv[64];
  int t = threadIdx.x;
  int s = t & 63, q = t >> 6;
  float acc = 0.f;
  for (int c = q*128; c < q*128 + 128; ++c)
    acc = fmaf(fb[c*HW + s], att_w[c], acc);
  part[q][s] = acc;
  __syncthreads();
  if (t < 64){
    float v = part[0][t] + part[1][t] + part[2][t] + part[3][t];
    float m = v;
    for (int o = 32; o > 0; o >>= 1) m = fmaxf(m, __shfl_xor(m, o));
    float e = __expf(v - m);
    float ssum = e;
    for (int o = 32; o > 0; o >>= 1) ssum += __shfl_xor(ssum, o);
    attv[t] = e / ssum * 2.0f;   // * BETA
  }
  __syncthreads();
  for (int c = t; c < FEAT; c += 256){
    const float4* row = (const float4*)(fb + c*HW);
    float a2 = 0.f;
    #pragma unroll
    for (int k = 0; k < 16; ++k){
      float4 v4 = row[k];
      a2 = fmaf(v4.x, attv[k*4+0], a2);
      a2 = fmaf(v4.y, attv[k*4+1], a2);
      a2 = fmaf(v4.z, attv[k*4+2], a2);
      a2 = fmaf(v4.w, attv[k*4+3], a2);
    }
    att_feat[(size_t)b*FEAT + c] = __float2bfloat16(a2);
  }
}

// ---------------- bf16 MFMA GEMM (NT) for gi_base preamble ----------------
__global__ __launch_bounds__(256) void gemm_mfma(const bf16_t* __restrict__ A,
                                                 const bf16_t* __restrict__ W,
                                                 const float* __restrict__ bias,
                                                 float* __restrict__ C,
                                                 int K, int lda, int ldw, int ldc){
  const int tid = threadIdx.x;
  const int w = tid >> 6, lane = tid & 63;
  const int r = lane & 15, half = lane >> 4;
  const int m_base = blockIdx.y * 64;
  const int n_base = blockIdx.x * 64 + w * 16;
  const bf16_t* Ap = A + (size_t)(m_base + r)*lda + half*8;
  const bf16_t* Wp = W + (size_t)(n_base + r)*ldw + half*8;
  f32x4 acc[4] = {};
  for (int k0 = 0; k0 < K; k0 += 32){
    bf16x8 bfrag = *(const bf16x8*)(Wp + k0);
    #pragma unroll
    for (int i = 0; i < 4; ++i){
      bf16x8 afrag = *(const bf16x8*)(Ap + (size_t)i*16*lda + k0);
      acc[i] = __builtin_amdgcn_mfma_f32_16x16x32_bf16(afrag, bfrag, acc[i], 0, 0, 0);
    }
  }
  const float bv = bias ? bias[n_base + r] : 0.f;
  #pragma unroll
  for (int i = 0; i < 4; ++i)
    #pragma unroll
    for (int q = 0; q < 4; ++q)
      C[(size_t)(m_base + i*16 + half*4 + q)*ldc + n_base + r] = acc[i][q] + bv;
}

// ---------------- the whole 32-step scan: one block owns 32 batch rows ----------------
__global__ __launch_bounds__(512) void mega_kernel(
    const float* __restrict__ gi_base,     // [B][1536] incl b_ih (+b_hh for r/z)
    const bf16_t* __restrict__ w_perm,     // [1536][576] permuted
    const bf16_t* __restrict__ w_ssn,      // [512][64]
    const bf16_t* __restrict__ lin1_wb,    // [512][512]
    const float* __restrict__ lin1_b,
    const bf16_t* __restrict__ lin2_wp,    // [48][512]
    const float* __restrict__ lin2_b,
    const float* __restrict__ b_hh,
    const float* __restrict__ gt,
    const int* __restrict__ line_prob,
    const float* __restrict__ sample_prob,
    float* __restrict__ out){
  __shared__ bf16_t lds_x[MB][LDX];    // [h(512) | ss(42) | zero-pad(22) | bank-pad(8)]
  __shared__ bf16_t hrelu[MB][LDH];
  __shared__ bf16_t o1s[MB][LDH];
  const int tid = threadIdx.x;
  const int w = tid >> 6, l = tid & 63;
  const int lr = l & 15, half = l >> 4;
  const int m0 = blockIdx.x * MB;

  // zero lds_x (h=0, ss=0 at t=0; pad cols stay 0 forever)
  for (int i = tid; i < MB*LDX/2; i += 512) ((uint32_t*)lds_x)[i] = 0u;

  // per-lane constants
  const int jc = w*64 + lr;           // column base within this wave's 64-col gate chunk
  float bhn[4];
  #pragma unroll
  for (int ti = 0; ti < 4; ++ti) bhn[ti] = b_hh[1024 + jc + ti*16];
  float lb1[4];
  #pragma unroll
  for (int ti = 0; ti < 4; ++ti) lb1[ti] = lin1_b[jc + ti*16];
  const int j3 = w*16 + lr;           // phase-C column (waves 0..2)
  const float b2 = (w < 3 && j3 < OUTSZ) ? lin2_b[j3] : 0.f;

  f32x4 hreg[2][4] = {};              // fp32 master h, lives in VGPRs across the scan

  const bf16_t* wp  = w_perm  + (size_t)(w*192 + lr)*KC + half*8;
  const bf16_t* wsp = w_ssn   + (size_t)(jc)*64 + half*8;
  const bf16_t* l1p = lin1_wb + (size_t)(jc)*512 + half*8;
  const bf16_t* l2p = lin2_wp + (size_t)(j3)*512 + half*8;

  __syncthreads();

  for (int t = 0; t < NL; ++t){
    // ---- Phase A: accA[mt][ti] = [h|ss] @ w_perm^T   (K=576, 18 k-steps)
    f32x4 accA[2][12] = {};
    #pragma unroll 2
    for (int k0 = 0; k0 < 18; ++k0){
      bf16x8 a0 = *(const bf16x8*)&lds_x[lr][k0*32 + half*8];
      bf16x8 a1 = *(const bf16x8*)&lds_x[16 + lr][k0*32 + half*8];
      #pragma unroll
      for (int ti = 0; ti < 12; ++ti){
        bf16x8 bf = *(const bf16x8*)(wp + (size_t)ti*16*KC + k0*32);
        accA[0][ti] = __builtin_amdgcn_mfma_f32_16x16x32_bf16(a0, bf, accA[0][ti], 0, 0, 0);
        accA[1][ti] = __builtin_amdgcn_mfma_f32_16x16x32_bf16(a1, bf, accA[1][ti], 0, 0, 0);
      }
    }
    // ---- ssn: input-side ss contribution to n gate (K=64)
    f32x4 accS[2][4] = {};
    #pragma unroll
    for (int k0 = 0; k0 < 2; ++k0){
      bf16x8 a0 = *(const bf16x8*)&lds_x[lr][512 + k0*32 + half*8];
      bf16x8 a1 = *(const bf16x8*)&lds_x[16 + lr][512 + k0*32 + half*8];
      #pragma unroll
      for (int ti = 0; ti < 4; ++ti){
        bf16x8 bf = *(const bf16x8*)(wsp + (size_t)ti*16*64 + k0*32);
        accS[0][ti] = __builtin_amdgcn_mfma_f32_16x16x32_bf16(a0, bf, accS[0][ti], 0, 0, 0);
        accS[1][ti] = __builtin_amdgcn_mfma_f32_16x16x32_bf16(a1, bf, accS[1][ti], 0, 0, 0);
      }
    }
    __syncthreads();   // everyone done reading lds_x before gates rewrite h-cols

    // ---- gates (per M-tile to bound register pressure)
    #pragma unroll
    for (int mt = 0; mt < 2; ++mt){
      const float* gbase = gi_base + (size_t)(m0 + mt*16 + half*4)*G3 + jc;
      float gbr[4][4], gbz[4][4], gbn[4][4];
      #pragma unroll
      for (int ti = 0; ti < 4; ++ti)
        #pragma unroll
        for (int q = 0; q < 4; ++q){
          const float* rp = gbase + (size_t)q*G3 + ti*16;
          gbr[ti][q] = rp[0];
          gbz[ti][q] = rp[512];
          gbn[ti][q] = rp[1024];
        }
      #pragma unroll
      for (int ti = 0; ti < 4; ++ti)
        #pragma unroll
        for (int q = 0; q < 4; ++q){
          float ir  = accA[mt][ti][q]     + gbr[ti][q];   // gb includes b_ih_r + b_hh_r
          float iz  = accA[mt][4+ti][q]   + gbz[ti][q];
          float hn  = accA[mt][8+ti][q]   + bhn[ti];
          float gin = gbn[ti][q]          + accS[mt][ti][q];
          float r = sigmoidf_(ir);
          float z = sigmoidf_(iz);
          float n = tanhf(gin + r*hn);
          float hv = (1.f - z)*n + z*hreg[mt][ti][q];
          hreg[mt][ti][q] = hv;
          int row = mt*16 + half*4 + q;
          int col = jc + ti*16;
          lds_x[row][col] = __float2bfloat16(hv);
          hrelu[row][col] = __float2bfloat16(fmaxf(hv, 0.f));
        }
    }
    __syncthreads();   // hrelu ready

    // ---- Phase B: o1 = relu(hrelu @ lin1^T + b1)  (K=512, 16 k-steps)
    {
      f32x4 accB[2][4] = {};
      #pragma unroll 2
      for (int k0 = 0; k0 < 16; ++k0){
        bf16x8 a0 = *(const bf16x8*)&hrelu[lr][k0*32 + half*8];
        bf16x8 a1 = *(const bf16x8*)&hrelu[16 + lr][k0*32 + half*8];
        #pragma unroll
        for (int ti = 0; ti < 4; ++ti){
          bf16x8 bf = *(const bf16x8*)(l1p + (size_t)ti*16*512 + k0*32);
          accB[0][ti] = __builtin_amdgcn_mfma_f32_16x16x32_bf16(a0, bf, accB[0][ti], 0, 0, 0);
          accB[1][ti] = __builtin_amdgcn_mfma_f32_16x16x32_bf16(a1, bf, accB[1][ti], 0, 0, 0);
        }
      }
      #pragma unroll
      for (int mt = 0; mt < 2; ++mt)
        #pragma unroll
        for (int ti = 0; ti < 4; ++ti)
          #pragma unroll
          for (int q = 0; q < 4; ++q){
            int row = mt*16 + half*4 + q;
            o1s[row][jc + ti*16] = __float2bfloat16(fmaxf(accB[mt][ti][q] + lb1[ti], 0.f));
          }
    }
    __syncthreads();   // o1 ready

    // ---- Phase C (waves 0..2): lin2 + outputs + ss_{t+1}
    if (w < 3){
      f32x4 accC[2] = {};
      #pragma unroll 2
      for (int k0 = 0; k0 < 16; ++k0){
        bf16x8 a0 = *(const bf16x8*)&o1s[lr][k0*32 + half*8];
        bf16x8 a1 = *(const bf16x8*)&o1s[16 + lr][k0*32 + half*8];
        bf16x8 bf = *(const bf16x8*)(l2p + k0*32);
        accC[0] = __builtin_amdgcn_mfma_f32_16x16x32_bf16(a0, bf, accC[0], 0, 0, 0);
        accC[1] = __builtin_amdgcn_mfma_f32_16x16x32_bf16(a1, bf, accC[1], 0, 0, 0);
      }
      #pragma unroll
      for (int mt = 0; mt < 2; ++mt)
        #pragma unroll
        for (int q = 0; q < 4; ++q){
          float val = accC[mt][q] + b2;
          int row = mt*16 + half*4 + q;
          int bm = m0 + row;
          if (j3 < 40){
            out[((size_t)bm*NL + t)*40 + j3] = val;
          } else if (j3 < 42){
            float other = __shfl_xor(val, 1);
            float m = fmaxf(val, other);
            float e0 = __expf(val - m), e1 = __expf(other - m);
            out[(size_t)B*NL*40 + ((size_t)bm*NL + t)*2 + (j3 - 40)] = e0/(e0 + e1);
          }
          if (t + 1 < NL && j3 < OUTSZ){
            bool up = sample_prob[(size_t)(t+1)*B + bm] < 0.1f;
            float gtv;
            if (j3 < 40) gtv = gt[((size_t)bm*NL + t)*40 + j3];
            else {
              float pv = (float)line_prob[bm*NL + t];
              gtv = (j3 == 40) ? 1.f - pv : pv;
            }
            lds_x[row][512 + j3] = __float2bfloat16(up ? val : gtv);
          }
        }
    }
    __syncthreads();   // ss ready for next step's phase A
  }
}

extern "C" void kernel_launch(void* const* d_in, const int* in_sizes, int n_in,
                              void* d_out, int out_size, void* d_ws, size_t ws_size,
                              hipStream_t stream) {
  const float* img         = (const float*)d_in[0];
  const float* gt          = (const float*)d_in[1];
  const int*   line_prob   = (const int*)d_in[2];
  const float* sample_prob = (const float*)d_in[3];
  const float* att_w       = (const float*)d_in[4];
  // d_in[5] att_b: unused — softmax shift-invariance cancels it
  const float* w_ih        = (const float*)d_in[6];
  const float* w_hh        = (const float*)d_in[7];
  const float* b_ih        = (const float*)d_in[8];
  const float* b_hh        = (const float*)d_in[9];
  const float* lin1_w      = (const float*)d_in[10];
  const float* lin1_b      = (const float*)d_in[11];
  const float* lin2_w      = (const float*)d_in[12];
  const float* lin2_b      = (const float*)d_in[13];
  float* out = (float*)d_out;

  char* p = (char*)d_ws;
  auto alloc = [&](size_t bytes){ void* q = p; p += (bytes + 255) & ~(size_t)255; return q; };
  float*  gi_base   = (float*)alloc((size_t)B*G3*4);
  bf16_t* att_bf    = (bf16_t*)alloc((size_t)B*FEAT*2);
  bf16_t* w_perm    = (bf16_t*)alloc((size_t)G3*KC*2);
  bf16_t* w_ssn     = (bf16_t*)alloc((size_t)512*64*2);
  bf16_t* lin1_wb   = (bf16_t*)alloc((size_t)512*512*2);
  bf16_t* lin2_wp   = (bf16_t*)alloc((size_t)48*512*2);
  bf16_t* w_ih512b  = (bf16_t*)alloc((size_t)G3*512*2);
  float*  bias_comb = (float*)alloc((size_t)G3*4);

  prep2_kernel<<<4096, 256, 0, stream>>>(w_ih, w_hh, lin1_w, lin2_w, b_ih, b_hh,
                                         w_perm, w_ssn, lin1_wb, lin2_wp,
                                         w_ih512b, bias_comb);
  att_kernel<<<B, 256, 0, stream>>>(img, att_w, att_bf);
  gemm_mfma<<<dim3(G3/64, B/64), 256, 0, stream>>>(att_bf, w_ih512b, bias_comb, gi_base,
                                                   512, 512, 512, G3);
  mega_kernel<<<NBLK, 512, 0, stream>>>(gi_base, w_perm, w_ssn, lin1_wb, lin1_b,
                                        lin2_wp, lin2_b, b_hh,
                                        gt, line_prob, sample_prob, out);
}